// Round 1
// baseline (255.713 us; speedup 1.0000x reference)
//
#include <hip/hip_runtime.h>

// out[b,k,l,f] = x[b, src(k,l), f], B=32, L=128, F=64, K=2L=256, fp32.
//   k <  L: src = (l - k) mod L   (cyclic)
//   k >= L: src = (k - l) mod L   (reflected)
//
// Round-3 SLICE-LINEAR multicast.
// Evidence: dur 251.3 us decomposes as ~162 us re-poison fill (rocprof top-5
// is ALL fillBuffer@162us; our kernel is absent -> kernel < 162us) + ~89 us
// kernel => stores run ~3 TB/s vs fillBuffer's 6.6 TB/s on the same buffer.
// Round-2's wave scattered 32 x 1 KiB store fragments across a 1 MiB span,
// with 8 blocks on 8 different XCDs interleaving the same region.
//
// Now: for k = kb + 16*m the needed source rows per thread are ONE fixed set
// of 8 rows, so block (b,kb) holds them in registers and writes 8 whole
// 32 KiB (b,k) slices END-TO-END LINEARLY (thread t -> slice_base + t +
// 256*j2 — the fillBuffer address pattern). The value's register index is
// (+/-(j2-m)) & 7: a compile-time constant after full unroll — no LDS, no
// per-store modulo, no runtime-indexed register array.
//
// Grid: 32 b x 32 kbsel = 1024 blocks x 256 thr (4 blocks/CU, 16 waves/CU).
// Per thread: 8 independent L2-hit loads, 64 independent stores.

__global__ __launch_bounds__(256) void SymmetryExpansion_kernel(
    const float4* __restrict__ x, float4* __restrict__ out) {
    unsigned t  = threadIdx.x;
    unsigned f4 = t & 15u;        // float4 chunk within F=64
    unsigned w  = t >> 4;         // l-group / row-group within block, 0..15

    unsigned blk   = blockIdx.x;
    unsigned kbsel = blk & 31u;   // 0..15 cyclic, 16..31 reflected
    unsigned b     = blk >> 5;    // batch

    bool refl   = (kbsel >= 16u);
    unsigned kb = refl ? (kbsel + 112u) : kbsel;  // 128..143 | 0..15

    // Held source rows:
    //   cyclic   : row_j = (w - kb + 16*j) mod 128
    //   reflected: row_j = (kb - w + 16*j) mod 128
    unsigned rbase = refl ? (kb - w) : (w + 128u - kb);

    // x is (32,128,64) fp32 -> float4 index (b<<11)|(row<<4)|f4
    const float4* xb = x + (b << 11) + f4;
    float4 r[8];
#pragma unroll
    for (unsigned j = 0; j < 8u; ++j)
        r[j] = xb[((rbase + (j << 4)) & 127u) << 4];

    // out float4 index: (b<<19)|(k<<11)|(l<<4)|f4. Slice m is k = kb+16m
    // (stride 16 slices = 1<<15 float4). Thread t's store offsets within a
    // slice are t + 256*j2 -> the workgroup covers the 32 KiB slice linearly.
    float4* ob = out + (b << 19) + (kb << 11) + t;
    if (!refl) {
        // value at l = w + 16*j2 is x[b,(l-k)&127] = r[(j2-m)&7]
#pragma unroll
        for (unsigned m = 0; m < 8u; ++m)
#pragma unroll
            for (unsigned j2 = 0; j2 < 8u; ++j2)
                ob[(m << 15) + (j2 << 8)] = r[(j2 - m) & 7u];
    } else {
        // value at l = w + 16*j2 is x[b,(k-l)&127] = r[(m-j2)&7]
#pragma unroll
        for (unsigned m = 0; m < 8u; ++m)
#pragma unroll
            for (unsigned j2 = 0; j2 < 8u; ++j2)
                ob[(m << 15) + (j2 << 8)] = r[(m - j2) & 7u];
    }
}

extern "C" void kernel_launch(void* const* d_in, const int* in_sizes, int n_in,
                              void* d_out, int out_size, void* d_ws, size_t ws_size,
                              hipStream_t stream) {
    const float4* x = (const float4*)d_in[0];
    float4* out = (float4*)d_out;
    dim3 grid(1024), block(256);
    hipLaunchKernelGGL(SymmetryExpansion_kernel, grid, block, 0, stream, x, out);
}